// Round 3
// baseline (251.405 us; speedup 1.0000x reference)
//
#include <hip/hip_runtime.h>
#include <hip/hip_cooperative_groups.h>

namespace cg = cooperative_groups;

#define SS 4096
#define DD 1024
#define LL 16
#define ROWF 1028   // LDS row stride in floats (4 KB + 16 B pad -> breaks 32-way bank alias)

typedef __attribute__((ext_vector_type(8))) short short8;
typedef __attribute__((ext_vector_type(4))) float fl4;

static __device__ __forceinline__ short f2bf(float f) {
    // round-to-nearest-even fp32 -> bf16 (inputs finite)
    unsigned u = __float_as_uint(f);
    u += 0x7FFFu + ((u >> 16) & 1u);
    return (short)(u >> 16);
}

static __device__ __forceinline__ short8 pack8(fl4 a, fl4 b) {
    short8 r;
    r[0] = f2bf(a[0]); r[1] = f2bf(a[1]); r[2] = f2bf(a[2]); r[3] = f2bf(a[3]);
    r[4] = f2bf(b[0]); r[5] = f2bf(b[1]); r[6] = f2bf(b[2]); r[7] = f2bf(b[3]);
    return r;
}

// Async global->LDS DMA: 16B/lane, per-lane src addr, dest = uniform base + lane*16.
static __device__ __forceinline__ void dma16(const float* g, float* l) {
    __builtin_amdgcn_global_load_lds(
        (const __attribute__((address_space(1))) void*)g,
        (__attribute__((address_space(3))) void*)l, 16, 0, 0);
}

// Single cooperative kernel: 256 blocks x 512 thr (8 waves, 1 block/CU,
// LDS-forced, exactly co-resident on 256 CUs).
// Phase 1 (per block, unchanged pipeline): 8 pairs of 16 s; raw s_barrier +
// counted vmcnt(8) keeps pair p+1's DMA in flight across pair p's compute.
//   B0 -> DMA p+1 -> vmcnt(8) -> B1 -> scores (4 x mfma_16x16x32_bf16/wave)
//   -> scr -> B2 -> distributed softmax (256 thr, one (s,l) each) -> e_lds,
//   per-thread z -> B3 -> PV fp32 fmac from LDS (ctx = 8 fl4 regs).
// Ends: Zpart[blk][l] (16 KB global); first 8 blocks zero out[].
// grid.sync()  (device-scope fence: Zpart + zeros visible everywhere)
// Phase 2: coef[l] = w[l]/Z[b][l]; weighted = sum_l coef*ctx (registers);
// one fl4 atomicAdd per thread into out[b][d]. No part buffer, no 2nd kernel.
// MFMA D layout: col(s)=lane&15, row(l)=(lane>>4)*4+reg  [m89-verified]
__global__ __launch_bounds__(512) void k_fused(const float* __restrict__ mem,
                                               const float* __restrict__ summ,
                                               const float* __restrict__ w,
                                               float* __restrict__ out,
                                               float* __restrict__ Zpart) {
    __shared__ float buf[2][16 * ROWF];   // 131.6 KB
    __shared__ float e_lds[16 * LL];      // 1 KB
    __shared__ float scr[8][256];         // 8 KB
    __shared__ float coef[LL];

    int blk = blockIdx.x;                 // 256 = 8 b x 32 segments
    int b   = blk >> 5;
    int s_base = (blk & 31) << 7;         // 128 s per block
    int t    = threadIdx.x;
    int wv   = t >> 6;                    // 0..7
    int lane = t & 63;
    int o  = lane & 15;
    int qd = lane >> 4;

    const float* gseg = mem + ((size_t)b * SS + s_base) * DD;

    // summ loads FIRST (issued before pair-0 DMAs -> consumption waits a
    // counted vmcnt, not a drain)
    fl4 a0[4], a1[4];
    {
        const float* arow = summ + o * DD + wv * 128 + qd * 8;
        #pragma unroll
        for (int j = 0; j < 4; ++j) {
            a0[j] = *(const fl4*)(arow + j * 32);
            a1[j] = *(const fl4*)(arow + j * 32 + 4);
        }
    }

    // Zero the (poisoned) output: 8 blocks x 256 thr x fl4 = 8x1024 floats.
    // Plain stores; grid.sync()'s device fence publishes them before any
    // phase-2 atomicAdd.
    if (blk < 8 && t < 256) *(fl4*)(out + blk * DD + t * 4) = (fl4){0.f, 0.f, 0.f, 0.f};

    // Prologue: DMA pair 0 (wave's share: rows 2wv, 2wv+1; 4 x 1KB chunks each)
    #pragma unroll
    for (int r = 0; r < 2; ++r) {
        int row = wv * 2 + r;
        #pragma unroll
        for (int c = 0; c < 4; ++c)
            dma16(gseg + (size_t)row * DD + c * 256 + lane * 4,
                  &buf[0][row * ROWF + c * 256]);
    }

    // A-frags in registers: wave wv covers K in [wv*128, wv*128+128)
    short8 afr[4];
    #pragma unroll
    for (int j = 0; j < 4; ++j) afr[j] = pack8(a0[j], a1[j]);

    int lg = t >> 8;                      // l-group: 0 -> l=0..7, 1 -> l=8..15
    int q  = t & 255;                     // owned d-quad
    // distributed-softmax role (threads 0..255): s_sm = t&15, l_sm = t>>4
    int s_sm = t & 15;
    int l_sm = (t >> 4) & 15;
    int scr_idx = ((l_sm >> 2) * 16 + s_sm) * 4 + (l_sm & 3);  // scr[.][lane'*4+r]

    fl4 ctx[8];
    #pragma unroll
    for (int l = 0; l < 8; ++l) ctx[l] = (fl4){0.f, 0.f, 0.f, 0.f};
    float z = 0.f;                        // per-thread Z partial (threads <256)
    const float scale = 0.03125f;         // 1/sqrt(1024)

    for (int p = 0; p < 8; ++p) {
        // B0: prior PV reads of buf[(p+1)&1] complete -> safe to DMA into it
        asm volatile("s_waitcnt lgkmcnt(0)" ::: "memory");
        __builtin_amdgcn_s_barrier();
        __builtin_amdgcn_sched_barrier(0);

        if (p < 7) {
            float* nbuf = &buf[(p + 1) & 1][0];
            const float* gp = gseg + (size_t)(p + 1) * 16 * DD;
            #pragma unroll
            for (int r = 0; r < 2; ++r) {
                int row = wv * 2 + r;
                #pragma unroll
                for (int c = 0; c < 4; ++c)
                    dma16(gp + (size_t)row * DD + c * 256 + lane * 4,
                          &nbuf[row * ROWF + c * 256]);
            }
            asm volatile("s_waitcnt vmcnt(8)" ::: "memory");  // pair p landed
        } else {
            asm volatile("s_waitcnt vmcnt(0)" ::: "memory");
        }
        __builtin_amdgcn_sched_barrier(0);
        __builtin_amdgcn_s_barrier();     // B1: pair p visible to all waves
        __builtin_amdgcn_sched_barrier(0);

        const float* bbase = &buf[p & 1][0];
        // scores: this wave's K=128 slice
        fl4 acc = {0.f, 0.f, 0.f, 0.f};
        const float* brow = bbase + o * ROWF + wv * 128 + qd * 8;
        #pragma unroll
        for (int j = 0; j < 4; ++j) {
            fl4 f0 = *(const fl4*)(brow + j * 32);
            fl4 f1 = *(const fl4*)(brow + j * 32 + 4);
            acc = __builtin_amdgcn_mfma_f32_16x16x32_bf16(afr[j], pack8(f0, f1),
                                                          acc, 0, 0, 0);
        }
        *(fl4*)&scr[wv][lane * 4] = acc;
        asm volatile("s_waitcnt lgkmcnt(0)" ::: "memory");
        __builtin_amdgcn_s_barrier();     // B2: partials visible
        __builtin_amdgcn_sched_barrier(0);

        // Distributed softmax: 256 threads, one (s,l) each
        if (t < 256) {
            float sum = 0.f;
            #pragma unroll
            for (int w8 = 0; w8 < 8; ++w8) sum += scr[w8][scr_idx];
            float ev = __expf(sum * scale);
            e_lds[s_sm * LL + l_sm] = ev;
            z += ev;
        }
        asm volatile("s_waitcnt lgkmcnt(0)" ::: "memory");
        __builtin_amdgcn_s_barrier();     // B3: e_lds ready
        __builtin_amdgcn_sched_barrier(0);

        // PV: thread owns d-quad q for l in [lg*8, lg*8+8); fp32 LDS operands
        const float* mrow = bbase + q * 4;
        const fl4* erow = (const fl4*)&e_lds[lg * 8];
        #pragma unroll 4
        for (int s = 0; s < 16; ++s) {
            fl4 m4 = *(const fl4*)(mrow + s * ROWF);
            fl4 e0 = erow[s * 4];         // e_lds[s*16 + lg*8 .. +3] (broadcast)
            fl4 e1 = erow[s * 4 + 1];     // e_lds[s*16 + lg*8+4 .. +7]
            #pragma unroll
            for (int j = 0; j < 4; ++j) {
                ctx[j]     += e0[j] * m4;
                ctx[4 + j] += e1[j] * m4;
            }
        }
    }

    // Z partials: threads 0..255 hold z for (s_sm, l_sm); reduce over s within
    // each 16-lane group; lane with s_sm==0 writes Zpart[blk*16 + l_sm]
    if (t < 256) {
        float v = z;
        v += __shfl_xor(v, 1, 64);
        v += __shfl_xor(v, 2, 64);
        v += __shfl_xor(v, 4, 64);
        v += __shfl_xor(v, 8, 64);
        if (s_sm == 0) Zpart[blk * LL + l_sm] = v;
    }

    // ---- grid-wide sync: Zpart + out-zeros visible device-wide ----
    cg::this_grid().sync();

    // Phase 2: coef[l] = w[l] / Z[b][l]; weight register ctx; one fl4
    // atomicAdd per thread into out[b][d] (64 adds/element, L2-resident).
    if (t < LL) {
        float Z = 0.f;
        #pragma unroll
        for (int s = 0; s < 32; ++s) Z += Zpart[(b * 32 + s) * LL + t];
        coef[t] = w[t] / Z;
    }
    __syncthreads();

    fl4 wsum = {0.f, 0.f, 0.f, 0.f};
    #pragma unroll
    for (int l = 0; l < 8; ++l) wsum += coef[lg * 8 + l] * ctx[l];

    float* op = out + (size_t)b * DD + q * 4;
    atomicAdd(op + 0, wsum[0]);
    atomicAdd(op + 1, wsum[1]);
    atomicAdd(op + 2, wsum[2]);
    atomicAdd(op + 3, wsum[3]);
}

extern "C" void kernel_launch(void* const* d_in, const int* in_sizes, int n_in,
                              void* d_out, int out_size, void* d_ws, size_t ws_size,
                              hipStream_t stream) {
    const float* mem  = (const float*)d_in[0];  // [8,4096,1024] fp32
    const float* summ = (const float*)d_in[1];  // [16,1024] fp32
    const float* w    = (const float*)d_in[2];  // [1,16] fp32
    float* out = (float*)d_out;                 // [8,1024] fp32
    float* Zpart = (float*)d_ws;                // 256*16 fl = 16 KB

    void* args[] = {(void*)&mem, (void*)&summ, (void*)&w, (void*)&out, (void*)&Zpart};
    hipLaunchCooperativeKernel((const void*)k_fused, dim3(256), dim3(512),
                               args, 0, stream);
}

// Round 4
// 218.235 us; speedup vs baseline: 1.1520x; 1.1520x over previous
//
#include <hip/hip_runtime.h>

#define SS 4096
#define DD 1024
#define LL 16
#define ROWF 1028   // LDS row stride in floats (4 KB + 16 B pad -> breaks 32-way bank alias)

typedef __attribute__((ext_vector_type(8))) short short8;
typedef __attribute__((ext_vector_type(4))) float fl4;

static __device__ __forceinline__ short f2bf(float f) {
    // round-to-nearest-even fp32 -> bf16 (inputs finite)
    unsigned u = __float_as_uint(f);
    u += 0x7FFFu + ((u >> 16) & 1u);
    return (short)(u >> 16);
}

static __device__ __forceinline__ short8 pack8(fl4 a, fl4 b) {
    short8 r;
    r[0] = f2bf(a[0]); r[1] = f2bf(a[1]); r[2] = f2bf(a[2]); r[3] = f2bf(a[3]);
    r[4] = f2bf(b[0]); r[5] = f2bf(b[1]); r[6] = f2bf(b[2]); r[7] = f2bf(b[3]);
    return r;
}

// Async global->LDS DMA: 16B/lane, per-lane src addr, dest = uniform base + lane*16.
static __device__ __forceinline__ void dma16(const float* g, float* l) {
    __builtin_amdgcn_global_load_lds(
        (const __attribute__((address_space(1))) void*)g,
        (__attribute__((address_space(3))) void*)l, 16, 0, 0);
}

// 256 blocks x 512 thr (8 waves, 1 block/CU LDS-forced).
// DEPTH-2 pipeline: PV no longer reads the LDS tile (reads the L2/L3-hot
// global copy via registers prefetched after B2), so buf[p&1] is free right
// after scores(p) -> DMA(p+2) issues at B2. Two pairs (128 KB/CU) of HBM
// fetch are continuously in flight. VMEM issue order per iter keeps DMAs
// YOUNGER than the m4 prefetch loads, so compiler-inserted waits for m4 uses
// are vmcnt(>=8) and never drain the DMA pipeline.
// Per iter p:
//   vmcnt(8) [pair p landed; pair p+1 flying] -> B1 -> scores: wave wv
//   K-slice [wv*128,+128), 4 x mfma_16x16x32_bf16 from LDS -> scr ->
//   lgkmcnt(0)+B2 -> m4 prefetch (16 fl4 from global, L2-hot) -> issue
//   DMA(p+2) into buf[p&1] -> distributed softmax (256 thr) -> e_lds ->
//   lgkmcnt(0)+B3 -> PV from m4 regs + e_lds broadcasts.
// MFMA D layout: col(s)=lane&15, row(l)=(lane>>4)*4+reg  [m89-verified]
__global__ __launch_bounds__(512) void k_main(const float* __restrict__ mem,
                                              const float* __restrict__ summ,
                                              float* __restrict__ part,
                                              float* __restrict__ Zpart) {
    __shared__ float buf[2][16 * ROWF];   // 131.6 KB
    __shared__ float e_lds[16 * LL];      // 1 KB
    __shared__ float scr[8][256];         // 8 KB

    int blk = blockIdx.x;                 // 256 = 8 b x 32 segments
    int b   = blk >> 5;
    int s_base = (blk & 31) << 7;         // 128 s per block
    int t    = threadIdx.x;
    int wv   = t >> 6;                    // 0..7
    int lane = t & 63;
    int o  = lane & 15;
    int qd = lane >> 4;

    const float* gseg = mem + ((size_t)b * SS + s_base) * DD;

    // summ loads FIRST (issued before DMAs -> consumption waits a counted
    // vmcnt, not a drain)
    fl4 a0[4], a1[4];
    {
        const float* arow = summ + o * DD + wv * 128 + qd * 8;
        #pragma unroll
        for (int j = 0; j < 4; ++j) {
            a0[j] = *(const fl4*)(arow + j * 32);
            a1[j] = *(const fl4*)(arow + j * 32 + 4);
        }
    }

    // Prologue: DMA pair 0 -> buf[0] AND pair 1 -> buf[1] (16 loads/wave)
    #pragma unroll
    for (int pp = 0; pp < 2; ++pp) {
        const float* gp = gseg + (size_t)pp * 16 * DD;
        #pragma unroll
        for (int r = 0; r < 2; ++r) {
            int row = wv * 2 + r;
            #pragma unroll
            for (int c = 0; c < 4; ++c)
                dma16(gp + (size_t)row * DD + c * 256 + lane * 4,
                      &buf[pp][row * ROWF + c * 256]);
        }
    }

    // A-frags in registers: wave wv covers K in [wv*128, wv*128+128)
    short8 afr[4];
    #pragma unroll
    for (int j = 0; j < 4; ++j) afr[j] = pack8(a0[j], a1[j]);

    int lg = t >> 8;                      // l-group: 0 -> l=0..7, 1 -> l=8..15
    int q  = t & 255;                     // owned d-quad
    // distributed-softmax role (threads 0..255): s_sm = t&15, l_sm = t>>4
    int s_sm = t & 15;
    int l_sm = (t >> 4) & 15;
    int scr_idx = ((l_sm >> 2) * 16 + s_sm) * 4 + (l_sm & 3);  // scr[.][lane'*4+r]

    fl4 ctx[8];
    #pragma unroll
    for (int l = 0; l < 8; ++l) ctx[l] = (fl4){0.f, 0.f, 0.f, 0.f};
    float z = 0.f;                        // per-thread Z partial (threads <256)
    const float scale = 0.03125f;         // 1/sqrt(1024)

    for (int p = 0; p < 8; ++p) {
        // Wait pair p (oldest 8 DMAs); pair p+1 stays in flight.
        if (p < 7) {
            asm volatile("s_waitcnt vmcnt(8)" ::: "memory");
        } else {
            asm volatile("s_waitcnt vmcnt(0)" ::: "memory");
        }
        __builtin_amdgcn_sched_barrier(0);
        __builtin_amdgcn_s_barrier();     // B1: pair p visible to all waves
        __builtin_amdgcn_sched_barrier(0);

        const float* bbase = &buf[p & 1][0];
        // scores: this wave's K=128 slice (LDS fp32 -> pack -> MFMA)
        fl4 acc = {0.f, 0.f, 0.f, 0.f};
        const float* brow = bbase + o * ROWF + wv * 128 + qd * 8;
        #pragma unroll
        for (int j = 0; j < 4; ++j) {
            fl4 f0 = *(const fl4*)(brow + j * 32);
            fl4 f1 = *(const fl4*)(brow + j * 32 + 4);
            acc = __builtin_amdgcn_mfma_f32_16x16x32_bf16(afr[j], pack8(f0, f1),
                                                          acc, 0, 0, 0);
        }
        *(fl4*)&scr[wv][lane * 4] = acc;
        asm volatile("s_waitcnt lgkmcnt(0)" ::: "memory");
        __builtin_amdgcn_s_barrier();     // B2: partials visible; buf[p&1] free
        __builtin_amdgcn_sched_barrier(0);

        // m4 prefetch: 2nd touch of tile p -> L2/L3-hot global. Issued BEFORE
        // DMA(p+2) so compiler waits for m4 uses count >=8 younger VMEM ops.
        fl4 m4r[16];
        const float* gtile = gseg + (size_t)p * 16 * DD + q * 4;
        #pragma unroll
        for (int s = 0; s < 16; ++s)
            m4r[s] = *(const fl4*)(gtile + (size_t)s * DD);
        __builtin_amdgcn_sched_barrier(0);

        if (p < 6) {                      // issue DMA(p+2) into freed slot
            float* nbuf = &buf[p & 1][0];
            const float* gp = gseg + (size_t)(p + 2) * 16 * DD;
            #pragma unroll
            for (int r = 0; r < 2; ++r) {
                int row = wv * 2 + r;
                #pragma unroll
                for (int c = 0; c < 4; ++c)
                    dma16(gp + (size_t)row * DD + c * 256 + lane * 4,
                          &nbuf[row * ROWF + c * 256]);
            }
        }
        __builtin_amdgcn_sched_barrier(0);

        // Distributed softmax: 256 threads, one (s,l) each
        if (t < 256) {
            float sum = 0.f;
            #pragma unroll
            for (int w8 = 0; w8 < 8; ++w8) sum += scr[w8][scr_idx];
            float ev = __expf(sum * scale);
            e_lds[s_sm * LL + l_sm] = ev;
            z += ev;
        }
        asm volatile("s_waitcnt lgkmcnt(0)" ::: "memory");
        __builtin_amdgcn_s_barrier();     // B3: e_lds ready
        __builtin_amdgcn_sched_barrier(0);

        // PV: thread owns d-quad q for l in [lg*8, lg*8+8); m4 from regs
        const fl4* erow = (const fl4*)&e_lds[lg * 8];
        #pragma unroll
        for (int s = 0; s < 16; ++s) {
            fl4 m4 = m4r[s];
            fl4 e0 = erow[s * 4];         // e_lds[s*16 + lg*8 .. +3] (broadcast)
            fl4 e1 = erow[s * 4 + 1];     // e_lds[s*16 + lg*8+4 .. +7]
            #pragma unroll
            for (int j = 0; j < 4; ++j) {
                ctx[j]     += e0[j] * m4;
                ctx[4 + j] += e1[j] * m4;
            }
        }
    }

    // Epilogue: unnormalized ctx partials (no atomics); layout = [blk][l][d]
    float* pp = part + (size_t)blk * LL * DD + (size_t)(lg * 8) * DD + q * 4;
    #pragma unroll
    for (int l = 0; l < 8; ++l) *(fl4*)(pp + (size_t)l * DD) = ctx[l];

    // Z: threads 0..255 hold z for (s_sm, l_sm); reduce over s within each
    // 16-lane group; lane with s_sm==0 writes Zpart[blk*16 + l_sm]
    if (t < 256) {
        float v = z;
        v += __shfl_xor(v, 1, 64);
        v += __shfl_xor(v, 2, 64);
        v += __shfl_xor(v, 4, 64);
        v += __shfl_xor(v, 8, 64);
        if (s_sm == 0) Zpart[blk * LL + l_sm] = v;
    }
}

// out[b][d] = sum_l (w[l] / sum_seg Zpart) * sum_seg part[b*32+seg][l][d]
// 256 blocks x 256 thr; fl4 loads (16B/lane)
__global__ __launch_bounds__(256) void k_out(const float* __restrict__ part,
                                             const float* __restrict__ Zpart,
                                             const float* __restrict__ w,
                                             float* __restrict__ out) {
    int blkid = blockIdx.x;          // 256 = 8 b x 32 d-chunks of 32
    int b  = blkid >> 5;
    int d0 = (blkid & 31) << 5;
    int t = threadIdx.x;
    __shared__ float coef[LL];
    __shared__ fl4 red[32][8];       // [seg][d-quad]

    if (t < LL) {
        float Z = 0.f;
        #pragma unroll
        for (int s = 0; s < 32; ++s) Z += Zpart[(b * 32 + s) * LL + t];
        coef[t] = w[t] / Z;
    }
    __syncthreads();

    int dq  = t & 7;                 // d-quad within 32-d chunk
    int seg = t >> 3;                // 0..31
    const float* pb = part + (size_t)(b * 32 + seg) * LL * DD + d0 + dq * 4;
    fl4 acc = {0.f, 0.f, 0.f, 0.f};
    #pragma unroll
    for (int l = 0; l < LL; ++l) {
        fl4 v = *(const fl4*)(pb + (size_t)l * DD);
        float c = coef[l];
        acc += c * v;
    }
    red[seg][dq] = acc;
    __syncthreads();

    if (t < 8) {
        fl4 s = {0.f, 0.f, 0.f, 0.f};
        #pragma unroll
        for (int g = 0; g < 32; ++g) s += red[g][t];
        *(fl4*)&out[b * DD + d0 + t * 4] = s;
    }
}

extern "C" void kernel_launch(void* const* d_in, const int* in_sizes, int n_in,
                              void* d_out, int out_size, void* d_ws, size_t ws_size,
                              hipStream_t stream) {
    const float* mem  = (const float*)d_in[0];  // [8,4096,1024] fp32
    const float* summ = (const float*)d_in[1];  // [16,1024] fp32
    const float* w    = (const float*)d_in[2];  // [1,16] fp32
    float* out = (float*)d_out;                 // [8,1024] fp32

    char* ws = (char*)d_ws;
    float* Zpart = (float*)ws;                  // 256*16 fl = 16 KB (pad to 64K)
    float* part  = (float*)(ws + 64 * 1024);    // 256*16*1024 fl = 16 MB

    k_main<<<256, 512, 0, stream>>>(mem, summ, part, Zpart);
    k_out<<<256, 256, 0, stream>>>(part, Zpart, w, out);
}

// Round 5
// 209.890 us; speedup vs baseline: 1.1978x; 1.0398x over previous
//
#include <hip/hip_runtime.h>

#define SS 4096
#define DD 1024
#define LL 16
#define ROWF 1028   // LDS row stride in floats (4 KB + 16 B pad)

typedef __attribute__((ext_vector_type(8))) short short8;
typedef __attribute__((ext_vector_type(4))) float fl4;

static __device__ __forceinline__ short f2bf(float f) {
    // round-to-nearest-even fp32 -> bf16 (inputs finite)
    unsigned u = __float_as_uint(f);
    u += 0x7FFFu + ((u >> 16) & 1u);
    return (short)(u >> 16);
}

static __device__ __forceinline__ short8 pack8(fl4 a, fl4 b) {
    short8 r;
    r[0] = f2bf(a[0]); r[1] = f2bf(a[1]); r[2] = f2bf(a[2]); r[3] = f2bf(a[3]);
    r[4] = f2bf(b[0]); r[5] = f2bf(b[1]); r[6] = f2bf(b[2]); r[7] = f2bf(b[3]);
    return r;
}

// Async global->LDS DMA: 16B/lane, per-lane src addr, dest = uniform base + lane*16.
static __device__ __forceinline__ void dma16(const float* g, float* l) {
    __builtin_amdgcn_global_load_lds(
        (const __attribute__((address_space(1))) void*)g,
        (__attribute__((address_space(3))) void*)l, 16, 0, 0);
}

// 256 blocks x 512 thr (8 waves, 1 block/CU LDS-forced).
// FINE-GRAINED pipeline: 16 granules of 8 s, 4 LDS buffers (32.9 KB each).
// DMA for granule g+3 issues at iter g => 3 granules (96 KB) in flight.
// PV DEFERRED by one granule: iter g runs PV(g-1) BEFORE the vmcnt wait for
// granule g, so PV's VALU work hides the residual fetch latency.
// Iter g:
//   PV(g-1) from buf[(g-1)&3] + e_lds          (all LDS, no waits)
//   vmcnt(8|4|0)  [granule g landed; g+1,g+2 stay in flight]
//   B1  (granule g visible; buf[(g-1)&3] free)
//   DMA(g+3) -> buf[(g+3)&3]                    (same slot as (g-1)&3)
//   scores(g): 4 x mfma_16x16x32_bf16 (B-cols 8..15 duplicate rows, ignored)
//   scr -> lgkm+B2 -> softmax (threads 0..127, one (s,l) each) -> e_lds, z
//   lgkm+B3
// Epilogue: PV(15); part/Zpart stores.
// MFMA D layout: col(s)=lane&15, row(l)=(lane>>4)*4+reg  [m89-verified]
__global__ __launch_bounds__(512) void k_main(const float* __restrict__ mem,
                                              const float* __restrict__ summ,
                                              float* __restrict__ part,
                                              float* __restrict__ Zpart) {
    __shared__ float buf[4][8 * ROWF];    // 131.6 KB
    __shared__ float e_lds[8 * LL];       // 0.5 KB
    __shared__ float scr[8][256];         // 8 KB

    int blk = blockIdx.x;                 // 256 = 8 b x 32 segments
    int b   = blk >> 5;
    int s_base = (blk & 31) << 7;         // 128 s per block
    int t    = threadIdx.x;
    int wv   = t >> 6;                    // 0..7
    int lane = t & 63;
    int o  = lane & 15;
    int qd = lane >> 4;

    const float* gseg = mem + ((size_t)b * SS + s_base) * DD;

    // summ loads FIRST (drained by pack8 below, before any DMA waits matter)
    fl4 a0[4], a1[4];
    {
        const float* arow = summ + o * DD + wv * 128 + qd * 8;
        #pragma unroll
        for (int j = 0; j < 4; ++j) {
            a0[j] = *(const fl4*)(arow + j * 32);
            a1[j] = *(const fl4*)(arow + j * 32 + 4);
        }
    }
    short8 afr[4];
    #pragma unroll
    for (int j = 0; j < 4; ++j) afr[j] = pack8(a0[j], a1[j]);

    // Prologue: DMA granules 0,1,2 (wave's share: row wv, 4 x 1KB chunks)
    #pragma unroll
    for (int g0 = 0; g0 < 3; ++g0) {
        const float* gp = gseg + (size_t)g0 * 8 * DD;
        #pragma unroll
        for (int c = 0; c < 4; ++c)
            dma16(gp + (size_t)wv * DD + c * 256 + lane * 4,
                  &buf[g0][wv * ROWF + c * 256]);
    }

    int lg = t >> 8;                      // l-group: 0 -> l=0..7, 1 -> l=8..15
    int q  = t & 255;                     // owned d-quad
    // softmax role (threads 0..127): s_sm = t&7, l_sm = (t>>3)&15
    int s_sm = t & 7;
    int l_sm = (t >> 3) & 15;
    int scr_idx = ((l_sm >> 2) * 16 + s_sm) * 4 + (l_sm & 3);  // scr[.][lane'*4+reg]

    fl4 ctx[8];
    #pragma unroll
    for (int l = 0; l < 8; ++l) ctx[l] = (fl4){0.f, 0.f, 0.f, 0.f};
    float z = 0.f;                        // per-thread Z partial (threads <128)
    const float scale = 0.03125f;         // 1/sqrt(1024)

    for (int g = 0; g < 16; ++g) {
        // ---- PV(g-1): fronts the fetch wait; pure LDS + VALU ----
        if (g > 0) {
            const float* mrow = &buf[(g - 1) & 3][0] + q * 4;
            const fl4* erow = (const fl4*)&e_lds[lg * 8];
            #pragma unroll
            for (int s = 0; s < 8; ++s) {
                fl4 m4 = *(const fl4*)(mrow + s * ROWF);
                fl4 e0 = erow[s * 4];     // e_lds[s*16 + lg*8 .. +3] (broadcast)
                fl4 e1 = erow[s * 4 + 1]; // e_lds[s*16 + lg*8+4 .. +7]
                #pragma unroll
                for (int j = 0; j < 4; ++j) {
                    ctx[j]     += e0[j] * m4;
                    ctx[4 + j] += e1[j] * m4;
                }
            }
        }
        // ---- wait granule g (oldest 4 DMAs); keep g+1,g+2 in flight ----
        asm volatile("s_waitcnt lgkmcnt(0)" ::: "memory");
        if (g <= 13)      asm volatile("s_waitcnt vmcnt(8)" ::: "memory");
        else if (g == 14) asm volatile("s_waitcnt vmcnt(4)" ::: "memory");
        else              asm volatile("s_waitcnt vmcnt(0)" ::: "memory");
        __builtin_amdgcn_sched_barrier(0);
        __builtin_amdgcn_s_barrier();     // B1: granule g visible; old buf free
        __builtin_amdgcn_sched_barrier(0);

        if (g <= 12) {                    // DMA(g+3) into the slot PV just freed
            const float* gp = gseg + (size_t)(g + 3) * 8 * DD;
            dma16(gp + (size_t)wv * DD +   0 + lane * 4, &buf[(g + 3) & 3][wv * ROWF +   0]);
            dma16(gp + (size_t)wv * DD + 256 + lane * 4, &buf[(g + 3) & 3][wv * ROWF + 256]);
            dma16(gp + (size_t)wv * DD + 512 + lane * 4, &buf[(g + 3) & 3][wv * ROWF + 512]);
            dma16(gp + (size_t)wv * DD + 768 + lane * 4, &buf[(g + 3) & 3][wv * ROWF + 768]);
        }
        __builtin_amdgcn_sched_barrier(0);

        // ---- scores(g): this wave's K=128 slice; rows o&7 (cols 8-15 dup) ----
        const float* bbase = &buf[g & 3][0];
        fl4 acc = {0.f, 0.f, 0.f, 0.f};
        const float* brow = bbase + (o & 7) * ROWF + wv * 128 + qd * 8;
        #pragma unroll
        for (int j = 0; j < 4; ++j) {
            fl4 f0 = *(const fl4*)(brow + j * 32);
            fl4 f1 = *(const fl4*)(brow + j * 32 + 4);
            acc = __builtin_amdgcn_mfma_f32_16x16x32_bf16(afr[j], pack8(f0, f1),
                                                          acc, 0, 0, 0);
        }
        *(fl4*)&scr[wv][lane * 4] = acc;
        asm volatile("s_waitcnt lgkmcnt(0)" ::: "memory");
        __builtin_amdgcn_s_barrier();     // B2: partials visible
        __builtin_amdgcn_sched_barrier(0);

        // ---- softmax: threads 0..127, one (s,l) each ----
        if (t < 128) {
            float sum = 0.f;
            #pragma unroll
            for (int w8 = 0; w8 < 8; ++w8) sum += scr[w8][scr_idx];
            float ev = __expf(sum * scale);
            e_lds[s_sm * LL + l_sm] = ev;
            z += ev;
        }
        asm volatile("s_waitcnt lgkmcnt(0)" ::: "memory");
        __builtin_amdgcn_s_barrier();     // B3: e_lds ready for PV at next iter
        __builtin_amdgcn_sched_barrier(0);
    }

    // ---- epilogue PV(15) ----
    {
        const float* mrow = &buf[15 & 3][0] + q * 4;
        const fl4* erow = (const fl4*)&e_lds[lg * 8];
        #pragma unroll
        for (int s = 0; s < 8; ++s) {
            fl4 m4 = *(const fl4*)(mrow + s * ROWF);
            fl4 e0 = erow[s * 4];
            fl4 e1 = erow[s * 4 + 1];
            #pragma unroll
            for (int j = 0; j < 4; ++j) {
                ctx[j]     += e0[j] * m4;
                ctx[4 + j] += e1[j] * m4;
            }
        }
    }

    // Unnormalized ctx partials; layout = [blk][l][d]
    float* pp = part + (size_t)blk * LL * DD + (size_t)(lg * 8) * DD + q * 4;
    #pragma unroll
    for (int l = 0; l < 8; ++l) *(fl4*)(pp + (size_t)l * DD) = ctx[l];

    // Z: threads 0..127 hold z for (s_sm, l_sm); reduce over s (xor 1,2,4);
    // lane with s_sm==0 writes Zpart[blk*16 + l_sm]
    if (t < 128) {
        float v = z;
        v += __shfl_xor(v, 1, 64);
        v += __shfl_xor(v, 2, 64);
        v += __shfl_xor(v, 4, 64);
        if (s_sm == 0) Zpart[blk * LL + l_sm] = v;
    }
}

// out[b][d] = sum_l (w[l] / sum_seg Zpart) * sum_seg part[b*32+seg][l][d]
// 256 blocks x 256 thr; fl4 loads (16B/lane)
__global__ __launch_bounds__(256) void k_out(const float* __restrict__ part,
                                             const float* __restrict__ Zpart,
                                             const float* __restrict__ w,
                                             float* __restrict__ out) {
    int blkid = blockIdx.x;          // 256 = 8 b x 32 d-chunks of 32
    int b  = blkid >> 5;
    int d0 = (blkid & 31) << 5;
    int t = threadIdx.x;
    __shared__ float coef[LL];
    __shared__ fl4 red[32][8];       // [seg][d-quad]

    if (t < LL) {
        float Z = 0.f;
        #pragma unroll
        for (int s = 0; s < 32; ++s) Z += Zpart[(b * 32 + s) * LL + t];
        coef[t] = w[t] / Z;
    }
    __syncthreads();

    int dq  = t & 7;                 // d-quad within 32-d chunk
    int seg = t >> 3;                // 0..31
    const float* pb = part + (size_t)(b * 32 + seg) * LL * DD + d0 + dq * 4;
    fl4 acc = {0.f, 0.f, 0.f, 0.f};
    #pragma unroll
    for (int l = 0; l < LL; ++l) {
        fl4 v = *(const fl4*)(pb + (size_t)l * DD);
        float c = coef[l];
        acc += c * v;
    }
    red[seg][dq] = acc;
    __syncthreads();

    if (t < 8) {
        fl4 s = {0.f, 0.f, 0.f, 0.f};
        #pragma unroll
        for (int g = 0; g < 32; ++g) s += red[g][t];
        *(fl4*)&out[b * DD + d0 + t * 4] = s;
    }
}

extern "C" void kernel_launch(void* const* d_in, const int* in_sizes, int n_in,
                              void* d_out, int out_size, void* d_ws, size_t ws_size,
                              hipStream_t stream) {
    const float* mem  = (const float*)d_in[0];  // [8,4096,1024] fp32
    const float* summ = (const float*)d_in[1];  // [16,1024] fp32
    const float* w    = (const float*)d_in[2];  // [1,16] fp32
    float* out = (float*)d_out;                 // [8,1024] fp32

    char* ws = (char*)d_ws;
    float* Zpart = (float*)ws;                  // 256*16 fl = 16 KB (pad to 64K)
    float* part  = (float*)(ws + 64 * 1024);    // 256*16*1024 fl = 16 MB

    k_main<<<256, 512, 0, stream>>>(mem, summ, part, Zpart);
    k_out<<<256, 256, 0, stream>>>(part, Zpart, w, out);
}